// Round 8
// baseline (317.402 us; speedup 1.0000x reference)
//
#include <hip/hip_runtime.h>
#include <hip/hip_bf16.h>
#include <stdint.h>

typedef __bf16 bf16x8 __attribute__((ext_vector_type(8)));
typedef float  f32x4  __attribute__((ext_vector_type(4)));
typedef short  s16x4  __attribute__((ext_vector_type(4)));

#define M_NODES 100000
#define K_IN    256
#define N_OUT   128
#define N_EDGE  1600000

// ---------------------------------------------------------------------------
// Stage 1: h[M,N] = in[M,K] @ w[K,N]. R8: A tile staged COALESCED into LDS.
//
// R6/R7 evidence: VGPR=120 (bfrag 64 + acc 32) leaves ~14 regs for A staging
// -> compiler serializes load->wait->cvt inside each k8; and the direct A
// loads are uncoalesced (lane reads row m0+mt*16+lr: one dwordx4 instruction
// touches 32 distinct 64B lines). Result: MfmaUtil 3%, VALUBusy 6%, 98% stall,
// and grid 512->1024 changed nothing (R7: latency chain, not wave count).
//
// Fix (canonical §5): stage A[64][256] fp32->bf16 into 32 KB LDS with
// coalesced loads (64 thr/row = 1 KB contiguous burst/row), cvt ONCE during
// staging (deletes 32 cvts/k8/wave), XOR-swizzle byte ^= (row&7)<<4 so the
// k-loop's ds_read_b128 (16 lanes at row-stride 512B) spreads across all 32
// banks (8 lanes/bank = b128 floor; unswizzled would be 4x worse).
// B panel stays in VGPRs (proven). Inner loop: 4 ds_read + 8 MFMA, no global.
// ---------------------------------------------------------------------------
template <bool FULL>
__device__ __forceinline__ void gemm_tile_lds(
    const float* __restrict__ in, float* __restrict__ h,
    __hip_bfloat16* __restrict__ hmir, short* __restrict__ smA,
    const bf16x8 (&bfrag)[8][2], const int m0, const int t,
    const int lr, const int q, const int nb)
{
    // ---- stage A tile: idx = i*256+t; row = idx>>6 (64 thr/row), kc = (idx&63)*4
    #pragma unroll
    for (int i = 0; i < 16; ++i) {
        const int idx = i * 256 + t;
        const int row = idx >> 6;
        const int kc  = (idx & 63) * 4;
        f32x4 v = f32x4{0.f, 0.f, 0.f, 0.f};
        if (FULL || (m0 + row) < M_NODES)
            v = *(const f32x4*)(in + (size_t)(m0 + row) * K_IN + kc);
        s16x4 p;
        #pragma unroll
        for (int j = 0; j < 4; ++j)
            p[j] = __builtin_bit_cast(short, (__bf16)v[j]);
        // swizzle flips byte bits 4-6 only; kc*2 is 8B-aligned, stays aligned
        const int byte = (row * 512 + kc * 2) ^ ((row & 7) << 4);
        *(s16x4*)((char*)smA + byte) = p;
    }
    __syncthreads();

    f32x4 acc[4][2];
    #pragma unroll
    for (int mt = 0; mt < 4; ++mt)
        #pragma unroll
        for (int nt = 0; nt < 2; ++nt)
            acc[mt][nt] = f32x4{0.f, 0.f, 0.f, 0.f};

    #pragma unroll
    for (int k8 = 0; k8 < 8; ++k8) {
        bf16x8 afrag[4];                     // A[m=mt*16+lr][k8*32+q*8 ..+7]
        #pragma unroll
        for (int mt = 0; mt < 4; ++mt) {
            const int row  = mt * 16 + lr;
            const int byte = (row * 512 + k8 * 64 + q * 16) ^ ((row & 7) << 4);
            afrag[mt] = *(const bf16x8*)((const char*)smA + byte);
        }
        #pragma unroll
        for (int mt = 0; mt < 4; ++mt)
            #pragma unroll
            for (int nt = 0; nt < 2; ++nt)
                acc[mt][nt] = __builtin_amdgcn_mfma_f32_16x16x32_bf16(
                    afrag[mt], bfrag[k8][nt], acc[mt][nt], 0, 0, 0);
    }

    // C/D: col = lane&15, row = (lane>>4)*4 + reg   (layout verified)
    #pragma unroll
    for (int mt = 0; mt < 4; ++mt) {
        const int rb = m0 + mt * 16 + q * 4;
        if (!FULL && rb >= M_NODES) continue; // M%4==0: rb<M => rb+3<M
        #pragma unroll
        for (int nt = 0; nt < 2; ++nt) {
            const int col = nb + nt * 16 + lr;
            #pragma unroll
            for (int r = 0; r < 4; ++r) {
                const float v = acc[mt][nt][r];
                __builtin_nontemporal_store(v, h + (size_t)(rb + r) * N_OUT + col);
                hmir[(size_t)(rb + r) * N_OUT + col] = __float2bfloat16(v);
            }
        }
    }
    __syncthreads();   // protect LDS against next tile's restaging
}

__global__ __launch_bounds__(256) void gemm_h_mfma(
    const float* __restrict__ in,            // [M,K] fp32
    const float* __restrict__ w,             // [K,N] fp32
    float* __restrict__ h,                   // [M,N] fp32 (d_out)
    __hip_bfloat16* __restrict__ hmir)       // [M,N] bf16 mirror (d_ws)
{
    __shared__ __align__(16) short smA[64 * 256];   // 32 KB, swizzled bf16

    const int t    = threadIdx.x;
    const int lane = t & 63;
    const int wave = t >> 6;                 // 0..3
    const int nb   = wave * 32;
    const int lr   = lane & 15;              // m (A) / n (B,C) within tile
    const int q    = lane >> 4;              // quad 0..3

    // Preload the wave's full B panel: bfrag[k8][nt][j] = w[k8*32+q*8+j][nb+nt*16+lr]
    bf16x8 bfrag[8][2];
    #pragma unroll
    for (int k8 = 0; k8 < 8; ++k8) {
        const int ka = k8 * 32 + q * 8;
        #pragma unroll
        for (int nt = 0; nt < 2; ++nt) {
            const int col = nb + nt * 16 + lr;
            #pragma unroll
            for (int j = 0; j < 8; ++j)
                bfrag[k8][nt][j] = (__bf16)w[(size_t)(ka + j) * N_OUT + col];
        }
    }

    const int ntiles = (M_NODES + 63) / 64;  // 1563
    const int nfull  = M_NODES / 64;         // 1562 guard-free tiles
    for (int tt = blockIdx.x; tt < ntiles; tt += gridDim.x) {
        const int m0 = tt * 64;
        if (tt < nfull)
            gemm_tile_lds<true >(in, h, hmir, smA, bfrag, m0, t, lr, q, nb);
        else
            gemm_tile_lds<false>(in, h, hmir, smA, bfrag, m0, t, lr, q, nb);
    }
}

// int64 edge indices < 1e5: every high word is 0. int32: odd words random.
__device__ inline int detect_i64(const uint32_t* p) {
    return __popcll(__ballot(p[2 * (threadIdx.x & 63) + 1] == 0u)) >= 60;
}

// ---------------------------------------------------------------------------
// Stage 2 (R1's proven form, single launch): 16 lanes/edge, 4 consecutive
// edges per group. ~98 µs = 344 MB of L2-miss fill @ the ~3.6 TB/s fabric
// ceiling (58% L2 hit on the 25.6 MB mirror). R2-R4 established bucketed
// reordering is net-negative at this size (prepass floor > fill savings).
// ---------------------------------------------------------------------------
__global__ __launch_bounds__(256) void edge_kernel_bf16(
    const __hip_bfloat16* __restrict__ hm,   // [M,N] bf16 mirror
    const uint32_t* __restrict__ edge_raw,   // [2,E] int64 or int32
    const float* __restrict__ a,             // [N] fp32
    float* __restrict__ ew,                  // [E] fp32 out
    int E)
{
    const int e64 = detect_i64(edge_raw);    // before any divergence/return
    const int s  = threadIdx.x & 15;
    const int g  = (int)((blockIdx.x * 256 + threadIdx.x) >> 4);
    const int e0 = g * 4;
    if (e0 >= E) return;

    const __bf16* hb = (const __bf16*)hm;
    const f32x4 a0 = *(const f32x4*)(a + s * 8);
    const f32x4 a1 = *(const f32x4*)(a + s * 8 + 4);

    if (e0 + 3 < E) {
        int srcs[4], dsts[4];
        if (e64) {
            const uint4 s01 = *(const uint4*)(edge_raw + 2 * (size_t)e0);
            const uint4 s23 = *(const uint4*)(edge_raw + 2 * (size_t)e0 + 4);
            const uint4 d01 = *(const uint4*)(edge_raw + 2 * ((size_t)E + e0));
            const uint4 d23 = *(const uint4*)(edge_raw + 2 * ((size_t)E + e0) + 4);
            srcs[0] = (int)s01.x; srcs[1] = (int)s01.z;
            srcs[2] = (int)s23.x; srcs[3] = (int)s23.z;
            dsts[0] = (int)d01.x; dsts[1] = (int)d01.z;
            dsts[2] = (int)d23.x; dsts[3] = (int)d23.z;
        } else {
            const int4 sv = *(const int4*)((const int*)edge_raw + e0);
            const int4 dv = *(const int4*)((const int*)edge_raw + (size_t)E + e0);
            srcs[0] = sv.x; srcs[1] = sv.y; srcs[2] = sv.z; srcs[3] = sv.w;
            dsts[0] = dv.x; dsts[1] = dv.y; dsts[2] = dv.z; dsts[3] = dv.w;
        }

        bf16x8 hs[4], hd[4];                 // 8 independent gathers in flight
        #pragma unroll
        for (int u = 0; u < 4; ++u) {
            hs[u] = *(const bf16x8*)(hb + (size_t)srcs[u] * N_OUT + s * 8);
            hd[u] = *(const bf16x8*)(hb + (size_t)dsts[u] * N_OUT + s * 8);
        }

        f32x4 rr;
        #pragma unroll
        for (int u = 0; u < 4; ++u) {
            float sum = 0.f;
            #pragma unroll
            for (int i = 0; i < 4; ++i)
                sum += fabsf((float)hs[u][i] - (float)hd[u][i]) * a0[i];
            #pragma unroll
            for (int i = 0; i < 4; ++i)
                sum += fabsf((float)hs[u][4 + i] - (float)hd[u][4 + i]) * a1[i];
            sum += __shfl_xor(sum, 1, 64);
            sum += __shfl_xor(sum, 2, 64);
            sum += __shfl_xor(sum, 4, 64);
            sum += __shfl_xor(sum, 8, 64);
            rr[u] = fmaxf(sum, 0.f);
        }
        if (s == 0) *(f32x4*)(ew + e0) = rr;
    } else {
        // tail (E not a multiple of 4): per-edge scalar path
        for (int e = e0; e < E; ++e) {
            int src, dst;
            if (e64) {
                src = (int)edge_raw[2 * (size_t)e];
                dst = (int)edge_raw[2 * ((size_t)E + e)];
            } else {
                const int* e32 = (const int*)edge_raw;
                src = e32[e];
                dst = e32[(size_t)E + e];
            }
            const bf16x8 hs = *(const bf16x8*)(hb + (size_t)src * N_OUT + s * 8);
            const bf16x8 hd = *(const bf16x8*)(hb + (size_t)dst * N_OUT + s * 8);
            float sum = 0.f;
            #pragma unroll
            for (int i = 0; i < 4; ++i)
                sum += fabsf((float)hs[i] - (float)hd[i]) * a0[i];
            #pragma unroll
            for (int i = 0; i < 4; ++i)
                sum += fabsf((float)hs[4 + i] - (float)hd[4 + i]) * a1[i];
            sum += __shfl_xor(sum, 1, 64);
            sum += __shfl_xor(sum, 2, 64);
            sum += __shfl_xor(sum, 4, 64);
            sum += __shfl_xor(sum, 8, 64);
            if (s == 0) ew[e] = fmaxf(sum, 0.f);
        }
    }
}

// fp32 fallback when d_ws can't hold the mirror.
__global__ __launch_bounds__(256) void edge_kernel_f32(
    const float* __restrict__ h,
    const uint32_t* __restrict__ edge_raw,
    const float* __restrict__ a,
    float* __restrict__ ew,
    int E)
{
    const int e64 = detect_i64(edge_raw);
    const int s = threadIdx.x & 15;
    const int e = (int)((blockIdx.x * 256 + threadIdx.x) >> 4);
    if (e >= E) return;

    int src, dst;
    if (e64) {
        src = (int)edge_raw[2 * (size_t)e];
        dst = (int)edge_raw[2 * ((size_t)E + e)];
    } else {
        const int* e32 = (const int*)edge_raw;
        src = e32[e];
        dst = e32[(size_t)E + e];
    }

    const f32x4 s0 = *(const f32x4*)(h + (size_t)src * N_OUT + s * 8);
    const f32x4 s1 = *(const f32x4*)(h + (size_t)src * N_OUT + s * 8 + 4);
    const f32x4 d0 = *(const f32x4*)(h + (size_t)dst * N_OUT + s * 8);
    const f32x4 d1 = *(const f32x4*)(h + (size_t)dst * N_OUT + s * 8 + 4);
    const f32x4 a0 = *(const f32x4*)(a + s * 8);
    const f32x4 a1 = *(const f32x4*)(a + s * 8 + 4);

    float sum = 0.f;
    #pragma unroll
    for (int i = 0; i < 4; ++i) sum += fabsf(s0[i] - d0[i]) * a0[i];
    #pragma unroll
    for (int i = 0; i < 4; ++i) sum += fabsf(s1[i] - d1[i]) * a1[i];

    sum += __shfl_xor(sum, 1, 64);
    sum += __shfl_xor(sum, 2, 64);
    sum += __shfl_xor(sum, 4, 64);
    sum += __shfl_xor(sum, 8, 64);

    if (s == 0) ew[e] = fmaxf(sum, 0.f);
}

extern "C" void kernel_launch(void* const* d_in, const int* in_sizes, int n_in,
                              void* d_out, int out_size, void* d_ws, size_t ws_size,
                              hipStream_t stream) {
    // d_in = { inputs fp32[100000,256], edge int64[2,E], weight fp32[256,128],
    //          a fp32[128,1] }   (documented dict order — validated R0-R6)
    // d_out = fp32: h[100000,128] then edge_weight[E].
    const float*    in   = (const float*)d_in[0];
    const uint32_t* edge = (const uint32_t*)d_in[1];
    const float*    w    = (const float*)d_in[2];
    const float*    a    = (const float*)d_in[3];

    float* h  = (float*)d_out;
    float* ew = h + (size_t)M_NODES * N_OUT;

    const size_t mirror_bytes = (size_t)M_NODES * N_OUT * sizeof(__hip_bfloat16);
    __hip_bfloat16* hmir =
        (ws_size >= mirror_bytes) ? (__hip_bfloat16*)d_ws : nullptr;

    if (hmir) {
        // grid=1024: 4 blocks/CU (VGPR ~130, LDS 32KB both permit it);
        // blocks 0..538 run 2 tiles, rest 1.
        gemm_h_mfma<<<dim3(1024), dim3(256), 0, stream>>>(in, w, h, hmir);
        const int egroups = (N_EDGE + 3) / 4;            // 4 edges / 16 lanes
        const int eblocks = (egroups * 16 + 255) / 256;  // 25000
        edge_kernel_bf16<<<dim3(eblocks), dim3(256), 0, stream>>>(
            hmir, edge, a, ew, N_EDGE);
    } else {
        gemm_h_mfma<<<dim3(1024), dim3(256), 0, stream>>>(
            in, w, h, (__hip_bfloat16*)d_ws);  // unreachable in practice
        const int eblocks = (N_EDGE * 16 + 255) / 256;
        edge_kernel_f32<<<dim3(eblocks), dim3(256), 0, stream>>>(
            h, edge, a, ew, N_EDGE);
    }
}

// Round 9
// 288.522 us; speedup vs baseline: 1.1001x; 1.1001x over previous
//
#include <hip/hip_runtime.h>
#include <hip/hip_bf16.h>
#include <stdint.h>

typedef __bf16 bf16x8 __attribute__((ext_vector_type(8)));
typedef float  f32x4  __attribute__((ext_vector_type(4)));

#define M_NODES 100000
#define K_IN    256
#define N_OUT   128
#define N_EDGE  1600000

// ---------------------------------------------------------------------------
// Stage 1 (R9): h[M,N] = in[M,K] @ w[K,N], wave-private-rows decomposition.
//
// Evidence trail: R6/R7 direct form = 77 µs (waves share the 64-row tile ->
// block reads A ~4x -> ~300+ MB extra fabric @3.6 TB/s). R5/R8 barriered
// restructures = 94-96 µs (each __syncthreads drains the prior tile's NT
// h-stores via in-order vmcnt). This version fixes BOTH:
//   - wave owns 16 rows x ALL 128 cols: its A rows are private -> A read
//     exactly ONCE, direct (uncoalesced-but-unamplified) loads, NO barriers
//     in the tile loop at all -> NT stores never drained mid-kernel.
//   - w lives in LDS (64 KB bf16), staged ONCE per block in MFMA-fragment
//     layout [k8][nt][q][lr][j]: the k-loop's ds_read_b128 is 1 KB
//     contiguous per instruction (conflict-free). ONE barrier per kernel,
//     before any global stores exist.
//   - staging scatter XORs lr*16 with nt<<4 (bits 4-6, 16B-granule,
//     bijective per 256B region) to spread the once-per-block ds_write_b16
//     pattern from 16-way to ~4-way conflicts. Read applies the same XOR.
// M_NODES % 16 == 0 -> boundary tile = whole-wave skip, no per-lane guards.
// C/D layout (verified): col = lane&15, row = (lane>>4)*4 + reg.
// ---------------------------------------------------------------------------
__global__ __launch_bounds__(256) void gemm_h_mfma(
    const float* __restrict__ in,            // [M,K] fp32
    const float* __restrict__ w,             // [K,N] fp32
    float* __restrict__ h,                   // [M,N] fp32 (d_out)
    __hip_bfloat16* __restrict__ hmir)       // [M,N] bf16 mirror (d_ws)
{
    __shared__ __align__(16) short smW[K_IN * N_OUT];   // 64 KB bf16 fragments

    const int t    = threadIdx.x;
    const int lane = t & 63;
    const int wv   = t >> 6;                 // 0..3: wave's 16-row slice
    const int lr   = lane & 15;
    const int q    = lane >> 4;              // quad 0..3

    // ---- stage w -> bf16 fragment layout (once per block, coalesced reads)
    // fragment byte addr for element (k, c):
    //   (k>>5)*8192 + (c>>4)*1024 + ((k>>3)&3)*256
    //   + (((c&15)*16) ^ ((c>>4)<<4)) + (k&7)*2
    #pragma unroll
    for (int i = 0; i < 32; ++i) {
        const int slot = i * 256 + t;        // 8192 f32x4 slots
        const int k    = slot >> 5;          // 0..255
        const int c0   = (slot & 31) * 4;    // 0..124, same nt for c0..c0+3
        const f32x4 v  = *(const f32x4*)(w + (size_t)k * N_OUT + c0);
        const int kb   = (k >> 5) * 8192 + ((k >> 3) & 3) * 256 + (k & 7) * 2;
        #pragma unroll
        for (int j = 0; j < 4; ++j) {
            const int c    = c0 + j;
            const int nt   = c >> 4;
            const int byte = kb + nt * 1024 + (((c & 15) * 16) ^ (nt << 4));
            *(short*)((char*)smW + byte) =
                __builtin_bit_cast(short, (__bf16)v[j]);
        }
    }
    __syncthreads();   // the ONLY barrier in this kernel (no stores yet)

    const int ntiles = (M_NODES + 63) / 64;  // 1563
    for (int tt = blockIdx.x; tt < ntiles; tt += gridDim.x) {
        const int mr = tt * 64 + wv * 16;    // wave's private 16-row base
        if (mr + 16 > M_NODES) continue;     // M%16==0: whole-wave granularity

        const int   row = mr + lr;           // this lane's A row (all k8)
        const float* ap = in + (size_t)row * K_IN;

        f32x4 acc[8];
        #pragma unroll
        for (int nt = 0; nt < 8; ++nt) acc[nt] = f32x4{0.f, 0.f, 0.f, 0.f};

        #pragma unroll
        for (int k8 = 0; k8 < 8; ++k8) {
            const int ka = k8 * 32 + q * 8;  // lane's 8 contiguous k
            const f32x4 a0 = *(const f32x4*)(ap + ka);
            const f32x4 a1 = *(const f32x4*)(ap + ka + 4);
            bf16x8 afrag;
            #pragma unroll
            for (int j = 0; j < 4; ++j) {
                afrag[j]     = (__bf16)a0[j];
                afrag[4 + j] = (__bf16)a1[j];
            }
            const int kbase = k8 * 8192 + q * 256;
            #pragma unroll
            for (int nt = 0; nt < 8; ++nt) {
                const int byte = kbase + nt * 1024 + ((lr * 16) ^ (nt << 4));
                const bf16x8 bfrag = *(const bf16x8*)((const char*)smW + byte);
                acc[nt] = __builtin_amdgcn_mfma_f32_16x16x32_bf16(
                    afrag, bfrag, acc[nt], 0, 0, 0);
            }
        }

        // C write: rows mr + q*4 + r, cols nt*16 + lr. No barrier follows —
        // NT stores drain only at kernel end.
        const int rb = mr + q * 4;
        #pragma unroll
        for (int nt = 0; nt < 8; ++nt) {
            const int col = nt * 16 + lr;
            #pragma unroll
            for (int r = 0; r < 4; ++r) {
                const float v = acc[nt][r];
                __builtin_nontemporal_store(v, h + (size_t)(rb + r) * N_OUT + col);
                hmir[(size_t)(rb + r) * N_OUT + col] = __float2bfloat16(v);
            }
        }
    }
}

// int64 edge indices < 1e5: every high word is 0. int32: odd words random.
__device__ inline int detect_i64(const uint32_t* p) {
    return __popcll(__ballot(p[2 * (threadIdx.x & 63) + 1] == 0u)) >= 60;
}

// ---------------------------------------------------------------------------
// Stage 2 (R1's proven form, single launch): 16 lanes/edge, 4 consecutive
// edges per group. ~98 µs = 344 MB of L2-miss fill @ the ~3.6 TB/s fabric
// ceiling (58% L2 hit on the 25.6 MB mirror). R2-R4 established bucketed
// reordering is net-negative at this size (prepass floor > fill savings).
// ---------------------------------------------------------------------------
__global__ __launch_bounds__(256) void edge_kernel_bf16(
    const __hip_bfloat16* __restrict__ hm,   // [M,N] bf16 mirror
    const uint32_t* __restrict__ edge_raw,   // [2,E] int64 or int32
    const float* __restrict__ a,             // [N] fp32
    float* __restrict__ ew,                  // [E] fp32 out
    int E)
{
    const int e64 = detect_i64(edge_raw);    // before any divergence/return
    const int s  = threadIdx.x & 15;
    const int g  = (int)((blockIdx.x * 256 + threadIdx.x) >> 4);
    const int e0 = g * 4;
    if (e0 >= E) return;

    const __bf16* hb = (const __bf16*)hm;
    const f32x4 a0 = *(const f32x4*)(a + s * 8);
    const f32x4 a1 = *(const f32x4*)(a + s * 8 + 4);

    if (e0 + 3 < E) {
        int srcs[4], dsts[4];
        if (e64) {
            const uint4 s01 = *(const uint4*)(edge_raw + 2 * (size_t)e0);
            const uint4 s23 = *(const uint4*)(edge_raw + 2 * (size_t)e0 + 4);
            const uint4 d01 = *(const uint4*)(edge_raw + 2 * ((size_t)E + e0));
            const uint4 d23 = *(const uint4*)(edge_raw + 2 * ((size_t)E + e0) + 4);
            srcs[0] = (int)s01.x; srcs[1] = (int)s01.z;
            srcs[2] = (int)s23.x; srcs[3] = (int)s23.z;
            dsts[0] = (int)d01.x; dsts[1] = (int)d01.z;
            dsts[2] = (int)d23.x; dsts[3] = (int)d23.z;
        } else {
            const int4 sv = *(const int4*)((const int*)edge_raw + e0);
            const int4 dv = *(const int4*)((const int*)edge_raw + (size_t)E + e0);
            srcs[0] = sv.x; srcs[1] = sv.y; srcs[2] = sv.z; srcs[3] = sv.w;
            dsts[0] = dv.x; dsts[1] = dv.y; dsts[2] = dv.z; dsts[3] = dv.w;
        }

        bf16x8 hs[4], hd[4];                 // 8 independent gathers in flight
        #pragma unroll
        for (int u = 0; u < 4; ++u) {
            hs[u] = *(const bf16x8*)(hb + (size_t)srcs[u] * N_OUT + s * 8);
            hd[u] = *(const bf16x8*)(hb + (size_t)dsts[u] * N_OUT + s * 8);
        }

        f32x4 rr;
        #pragma unroll
        for (int u = 0; u < 4; ++u) {
            float sum = 0.f;
            #pragma unroll
            for (int i = 0; i < 4; ++i)
                sum += fabsf((float)hs[u][i] - (float)hd[u][i]) * a0[i];
            #pragma unroll
            for (int i = 0; i < 4; ++i)
                sum += fabsf((float)hs[u][4 + i] - (float)hd[u][4 + i]) * a1[i];
            sum += __shfl_xor(sum, 1, 64);
            sum += __shfl_xor(sum, 2, 64);
            sum += __shfl_xor(sum, 4, 64);
            sum += __shfl_xor(sum, 8, 64);
            rr[u] = fmaxf(sum, 0.f);
        }
        if (s == 0) *(f32x4*)(ew + e0) = rr;
    } else {
        // tail (E not a multiple of 4): per-edge scalar path
        for (int e = e0; e < E; ++e) {
            int src, dst;
            if (e64) {
                src = (int)edge_raw[2 * (size_t)e];
                dst = (int)edge_raw[2 * ((size_t)E + e)];
            } else {
                const int* e32 = (const int*)edge_raw;
                src = e32[e];
                dst = e32[(size_t)E + e];
            }
            const bf16x8 hs = *(const bf16x8*)(hb + (size_t)src * N_OUT + s * 8);
            const bf16x8 hd = *(const bf16x8*)(hb + (size_t)dst * N_OUT + s * 8);
            float sum = 0.f;
            #pragma unroll
            for (int i = 0; i < 4; ++i)
                sum += fabsf((float)hs[i] - (float)hd[i]) * a0[i];
            #pragma unroll
            for (int i = 0; i < 4; ++i)
                sum += fabsf((float)hs[4 + i] - (float)hd[4 + i]) * a1[i];
            sum += __shfl_xor(sum, 1, 64);
            sum += __shfl_xor(sum, 2, 64);
            sum += __shfl_xor(sum, 4, 64);
            sum += __shfl_xor(sum, 8, 64);
            if (s == 0) ew[e] = fmaxf(sum, 0.f);
        }
    }
}

// fp32 fallback when d_ws can't hold the mirror.
__global__ __launch_bounds__(256) void edge_kernel_f32(
    const float* __restrict__ h,
    const uint32_t* __restrict__ edge_raw,
    const float* __restrict__ a,
    float* __restrict__ ew,
    int E)
{
    const int e64 = detect_i64(edge_raw);
    const int s = threadIdx.x & 15;
    const int e = (int)((blockIdx.x * 256 + threadIdx.x) >> 4);
    if (e >= E) return;

    int src, dst;
    if (e64) {
        src = (int)edge_raw[2 * (size_t)e];
        dst = (int)edge_raw[2 * ((size_t)E + e)];
    } else {
        const int* e32 = (const int*)edge_raw;
        src = e32[e];
        dst = e32[(size_t)E + e];
    }

    const f32x4 s0 = *(const f32x4*)(h + (size_t)src * N_OUT + s * 8);
    const f32x4 s1 = *(const f32x4*)(h + (size_t)src * N_OUT + s * 8 + 4);
    const f32x4 d0 = *(const f32x4*)(h + (size_t)dst * N_OUT + s * 8);
    const f32x4 d1 = *(const f32x4*)(h + (size_t)dst * N_OUT + s * 8 + 4);
    const f32x4 a0 = *(const f32x4*)(a + s * 8);
    const f32x4 a1 = *(const f32x4*)(a + s * 8 + 4);

    float sum = 0.f;
    #pragma unroll
    for (int i = 0; i < 4; ++i) sum += fabsf(s0[i] - d0[i]) * a0[i];
    #pragma unroll
    for (int i = 0; i < 4; ++i) sum += fabsf(s1[i] - d1[i]) * a1[i];

    sum += __shfl_xor(sum, 1, 64);
    sum += __shfl_xor(sum, 2, 64);
    sum += __shfl_xor(sum, 4, 64);
    sum += __shfl_xor(sum, 8, 64);

    if (s == 0) ew[e] = fmaxf(sum, 0.f);
}

extern "C" void kernel_launch(void* const* d_in, const int* in_sizes, int n_in,
                              void* d_out, int out_size, void* d_ws, size_t ws_size,
                              hipStream_t stream) {
    // d_in = { inputs fp32[100000,256], edge int64[2,E], weight fp32[256,128],
    //          a fp32[128,1] }   (documented dict order — validated R0-R6)
    // d_out = fp32: h[100000,128] then edge_weight[E].
    const float*    in   = (const float*)d_in[0];
    const uint32_t* edge = (const uint32_t*)d_in[1];
    const float*    w    = (const float*)d_in[2];
    const float*    a    = (const float*)d_in[3];

    float* h  = (float*)d_out;
    float* ew = h + (size_t)M_NODES * N_OUT;

    const size_t mirror_bytes = (size_t)M_NODES * N_OUT * sizeof(__hip_bfloat16);
    __hip_bfloat16* hmir =
        (ws_size >= mirror_bytes) ? (__hip_bfloat16*)d_ws : nullptr;

    if (hmir) {
        // grid=512: 64 KB LDS -> 2 blocks/CU exactly; ~3 tiles/block
        // amortize the one-time w staging.
        gemm_h_mfma<<<dim3(512), dim3(256), 0, stream>>>(in, w, h, hmir);
        const int egroups = (N_EDGE + 3) / 4;            // 4 edges / 16 lanes
        const int eblocks = (egroups * 16 + 255) / 256;  // 25000
        edge_kernel_bf16<<<dim3(eblocks), dim3(256), 0, stream>>>(
            hmir, edge, a, ew, N_EDGE);
    } else {
        gemm_h_mfma<<<dim3(512), dim3(256), 0, stream>>>(
            in, w, h, (__hip_bfloat16*)d_ws);  // unreachable in practice
        const int eblocks = (N_EDGE * 16 + 255) / 256;
        edge_kernel_f32<<<dim3(eblocks), dim3(256), 0, stream>>>(
            h, edge, a, ew, N_EDGE);
    }
}